// Round 11
// baseline (204.001 us; speedup 1.0000x reference)
//
#include <hip/hip_runtime.h>
#include <hip/hip_bf16.h>
#include <math.h>

// Problem constants
#define BATCH 8192
#define NB 9
#define NN 256
#define PMAX 8
#define HID 32
#define ZDIM 2304   // NB*NN

typedef short bf16x8 __attribute__((ext_vector_type(8)));   // 8 bf16 in 4 VGPRs
typedef float f32x4 __attribute__((ext_vector_type(4)));    // MFMA accumulator

static __device__ inline unsigned short f2bf(float f) {
    __hip_bfloat16 h = __float2bfloat16(f);
    return *reinterpret_cast<unsigned short*>(&h);
}

static __device__ inline uint4 pack8(float4 a, float4 b) {
    uint4 u;
    u.x = (unsigned)f2bf(a.x) | ((unsigned)f2bf(a.y) << 16);
    u.y = (unsigned)f2bf(a.z) | ((unsigned)f2bf(a.w) << 16);
    u.z = (unsigned)f2bf(b.x) | ((unsigned)f2bf(b.y) << 16);
    u.w = (unsigned)f2bf(b.z) | ((unsigned)f2bf(b.w) << 16);
    return u;
}

// ---------------- K0: pack weights to bf16 fragment layouts --------------------
// Wf : W   in B-fragment order by z-col chunk kc=(7-r)*8+j/32  (hi, r9-proven)
// WTf: W^T in B-fragment order by (k=7-r, chunk c=i/32, colgroup j/16)  (lo)
//      value W[r][i][j] -> WTf[(((7-r)*8+(i>>5))*16+(j>>4))*64 + (j&15)+16*((i>>3)&3)],
//      elem i&7.  Consumer: B[n][kk]=W[7-k][kk][n], lane=(n&15)+16*(kk>>3).
__global__ __launch_bounds__(256) void k_pack(
    const float* __restrict__ W, const float* __restrict__ gW1,
    unsigned short* __restrict__ Wf, unsigned short* __restrict__ WTf,
    unsigned short* __restrict__ gW1b, unsigned short* __restrict__ g1Tb) {
    int r = blockIdx.z;
    int t = threadIdx.x;
    if (r < 8) {
        int i0 = blockIdx.y * 32;
        int j0 = blockIdx.x * 32;
        int tx = t & 31;
        int ty = t >> 5;
        const float* src = W + (size_t)r * 65536;
        int kc2b = ((7 - r) << 3) + (j0 >> 5);   // Wf kc for this j-block
        int j = j0 + tx;
        #pragma unroll
        for (int s = 0; s < 32; s += 8) {
            int i = i0 + ty + s;
            float v = src[(size_t)i * 256 + j];
            unsigned short b = f2bf(v);
            size_t widx = ((size_t)(kc2b * 16 + (i >> 4)) * 64
                           + ((i & 15) + 16 * ((j >> 3) & 3))) * 8 + (j & 7);
            Wf[widx] = b;
            size_t tidx = ((size_t)(((7 - r) * 8 + (i >> 5)) * 16 + (j >> 4)) * 64
                           + ((j & 15) + 16 * ((i >> 3) & 3))) * 8 + (i & 7);
            WTf[tidx] = b;
        }
    } else {
        int tg = (blockIdx.y * 8 + blockIdx.x) * 256 + t;       // 0..16383
        for (int e = tg; e < 73728; e += 16384) {
            float v = gW1[e];
            unsigned short b = f2bf(v);
            gW1b[e] = b;
            int k = e >> 13, n = (e >> 5) & 255, h = e & 31;
            g1Tb[(size_t)(k * 32 + h) * 256 + n] = b;
        }
    }
}

// -------------------- K1 (MFMA): d1f[k] = bf16(silu'(a1) * upstream) ----------
// All 8 z-chunks preloaded to registers up front (HBM latency overlaps the
// B/W2 staging VALU work); ONE barrier; then 16 back-to-back MFMAs.
// Side-products: zf (bf16 A-fragment z), d1f (bf16 A-fragment d1).
__global__ __launch_bounds__(256) void k_mlp(
    const float* __restrict__ z, const unsigned short* __restrict__ g1Tb,
    const float* __restrict__ gb1, const float* __restrict__ gW2,
    const float* __restrict__ gb2, const float* __restrict__ gW3,
    unsigned short* __restrict__ d1f, unsigned short* __restrict__ zf) {
    __shared__ uint4 Az[8][256];  // 32 KB: 8 chunks x (64 rows x 32k bf16); Az[0] reused h1/da2/d1
    __shared__ uint4 Bw[1024];    // gW1^T block: 32 h x 256 n bf16
    __shared__ uint4 W2Ts4[128];  // W2^T fragment
    __shared__ uint4 W2Ns4[128];  // W2 natural fragment

    int t = threadIdx.x;
    int lane = t & 63;
    int w = t >> 6;
    int k = blockIdx.y;
    int b0 = blockIdx.x * 64;
    uint4* zfu = (uint4*)zf;
    uint4* d1fu = (uint4*)d1f;
    int rb0 = b0 >> 4;

    int mq = t >> 2;                                 // row 0..63
    int q = t & 3;
    int ci0 = (mq & 15) + 16 * q + 64 * (mq >> 4);   // fragment index 0..255

    // ---- 1) issue all 8 z-chunk loads ----
    float4 fa[8][2];
    #pragma unroll
    for (int c = 0; c < 8; ++c) {
        const float* as = z + (size_t)(b0 + mq) * ZDIM + k * 256 + c * 32 + q * 8;
        fa[c][0] = *(const float4*)(as);
        fa[c][1] = *(const float4*)(as + 4);
    }

    // ---- 2) stage B (gW1^T) and W2 tiles (covers z-load latency) ----
    const unsigned short* bsrc = g1Tb + (size_t)k * 8192;
    for (int e = t; e < 1024; e += 256) {
        int h = e >> 5;
        int rest = e & 31;
        int c = rest >> 2, qq = rest & 3;
        Bw[c * 128 + (h & 15) + 16 * qq + 64 * (h >> 4)] =
            *(const uint4*)(bsrc + (size_t)h * 256 + c * 32 + qq * 8);
    }
    const float* gw2 = gW2 + (size_t)k * 1024;
    unsigned short* w2t = (unsigned short*)W2Ts4;
    unsigned short* w2n = (unsigned short*)W2Ns4;
    for (int e = t; e < 1024; e += 256) {
        int n = e >> 5, kk = e & 31;
        int qq = kk >> 3, jj = kk & 7;
        int ci = (n & 15) + 16 * qq + 64 * (n >> 4);
        w2t[ci * 8 + jj] = f2bf(gw2[kk * 32 + n]);   // W2T[g=n][h=kk]
        w2n[ci * 8 + jj] = f2bf(gw2[n * 32 + kk]);   // W2N[h=n][g=kk]
    }

    // ---- 3) pack + store all chunks (Az + zf) ----
    #pragma unroll
    for (int c = 0; c < 8; ++c) {
        uint4 pk = pack8(fa[c][0], fa[c][1]);
        Az[c][ci0] = pk;
        zfu[((size_t)(rb0 + (ci0 >> 6)) * 72 + (k * 8 + c)) * 64 + (ci0 & 63)] = pk;
    }
    __syncthreads();             // Bw/W2 cooperative staging + Az ready

    // ---- 4) layer-1: acc1 = z_k @ gW1[k], no barriers ----
    f32x4 acc1[2];
    #pragma unroll
    for (int j = 0; j < 2; ++j) acc1[j] = (f32x4){0.f, 0.f, 0.f, 0.f};
    #pragma unroll
    for (int c = 0; c < 8; ++c) {
        bf16x8 af = __builtin_bit_cast(bf16x8, Az[c][w * 64 + lane]);
        #pragma unroll
        for (int j = 0; j < 2; ++j)
            acc1[j] = __builtin_amdgcn_mfma_f32_16x16x32_bf16(
                af, __builtin_bit_cast(bf16x8, Bw[c * 128 + lane + j * 64]), acc1[j], 0, 0, 0);
    }

    // ---- bias + silu; keep silu'(a1); h1 -> Az[0] (fragment-order bf16) ----
    int cq = lane >> 4;
    int ci16 = lane & 15;
    float b1v[2], b2v[2], g3v[2];
    #pragma unroll
    for (int j = 0; j < 2; ++j) {
        b1v[j] = gb1[k * 32 + j * 16 + ci16];
        b2v[j] = gb2[k * 32 + j * 16 + ci16];
        g3v[j] = gW3[k * 32 + j * 16 + ci16];
    }
    unsigned short* Hs = (unsigned short*)Az;        // Az[0] 64x32 bf16 tile
    float sp1[2][4];
    __syncthreads();             // all Az[c] fragment reads done
    #pragma unroll
    for (int j = 0; j < 2; ++j)
        #pragma unroll
        for (int r = 0; r < 4; ++r) {
            float a1 = acc1[j][r] + b1v[j];
            float s1 = 1.f / (1.f + __expf(-a1));
            sp1[j][r] = s1 * (1.f + a1 * (1.f - s1));
            int col = j * 16 + ci16;
            int chunk = (cq * 4 + r) + 16 * (col >> 3) + 64 * w;
            Hs[chunk * 8 + (col & 7)] = f2bf(a1 * s1);
        }
    __syncthreads();

    // ---- layer-2: a2 = h1 @ W2 ----
    bf16x8 af2 = __builtin_bit_cast(bf16x8, Az[0][w * 64 + lane]);
    f32x4 acc2[2];
    #pragma unroll
    for (int j = 0; j < 2; ++j) {
        acc2[j] = (f32x4){0.f, 0.f, 0.f, 0.f};
        acc2[j] = __builtin_amdgcn_mfma_f32_16x16x32_bf16(
            af2, __builtin_bit_cast(bf16x8, W2Ts4[lane + j * 64]), acc2[j], 0, 0, 0);
    }

    // ---- da2 = gW3 * silu'(a2) -> Az[0] ----
    __syncthreads();             // h1 reads done
    #pragma unroll
    for (int j = 0; j < 2; ++j)
        #pragma unroll
        for (int r = 0; r < 4; ++r) {
            float a2 = acc2[j][r] + b2v[j];
            float s2 = 1.f / (1.f + __expf(-a2));
            float da2 = g3v[j] * s2 * (1.f + a2 * (1.f - s2));
            int col = j * 16 + ci16;
            int chunk = (cq * 4 + r) + 16 * (col >> 3) + 64 * w;
            Hs[chunk * 8 + (col & 7)] = f2bf(da2);
        }
    __syncthreads();

    // ---- layer-3: dh1 = da2 @ W2^T; d1 = bf16(dh1 * silu'(a1)) -> Az[0] -> d1f
    bf16x8 af3 = __builtin_bit_cast(bf16x8, Az[0][w * 64 + lane]);
    __syncthreads();             // da2 fragments in regs before overwrite
    #pragma unroll
    for (int j = 0; j < 2; ++j) {
        f32x4 a3 = (f32x4){0.f, 0.f, 0.f, 0.f};
        a3 = __builtin_amdgcn_mfma_f32_16x16x32_bf16(
            af3, __builtin_bit_cast(bf16x8, W2Ns4[lane + j * 64]), a3, 0, 0, 0);
        #pragma unroll
        for (int r = 0; r < 4; ++r) {
            int col = j * 16 + ci16;
            int chunk = (cq * 4 + r) + 16 * (col >> 3) + 64 * w;
            Hs[chunk * 8 + (col & 7)] = f2bf(a3[r] * sp1[j][r]);
        }
    }
    __syncthreads();
    // cooperative coalesced store: Az[0] chunk layout == A-fragment layout
    d1fu[((size_t)k * 512 + rb0 + (t >> 6)) * 64 + (t & 63)] = Az[0][t];
}

// ---- K2 (MFMA, barrier-free): out[:, 0:2048] ----------------------------------
// Wave-independent 16x64 strips, K=288 (8 z8-chunks + d1 tail), zero LDS/barriers,
// depth-3 register prefetch. A from zf chunks 64..71, tail d1f; B from WTf,
// tail gW1b. All fragment-ordered -> 1 KB coalesced wave transactions.
// Grid (x=128 rows, y=32 cols): same-A col-WGs differ by 128 == 0 mod 8 XCDs.
__global__ __launch_bounds__(256) void k_gemm_lo(
    const unsigned short* __restrict__ zf, const unsigned short* __restrict__ d1f,
    const unsigned short* __restrict__ WTf, const unsigned short* __restrict__ gW1b,
    float* __restrict__ out) {
    int t = threadIdx.x;
    int lane = t & 63;
    int w = t >> 6;
    int b0 = blockIdx.x * 64;    // batch rows
    int i0 = blockIdx.y * 64;    // output cols 0..2047
    int k  = i0 >> 8;            // z-block 0..7
    int g0 = (i0 >> 4) & 15;     // col group base within block
    int rl = lane & 15;
    int kq = lane >> 4;
    int rb = (b0 >> 4) + w;

    const uint4* Abase = (const uint4*)zf + ((size_t)rb * 72 + 64) * 64 + lane;
    const uint4* Atail = (const uint4*)d1f + ((size_t)k * 512 + rb) * 64 + lane;
    const uint4* Bbase = (const uint4*)WTf + ((size_t)(k * 8) * 16 + g0) * 64 + lane;
    const unsigned short* Btail = gW1b + ((size_t)(k * 256) + (i0 & 255) + rl) * 32 + kq * 8;

    f32x4 acc[4];
    #pragma unroll
    for (int j = 0; j < 4; ++j) acc[j] = (f32x4){0.f, 0.f, 0.f, 0.f};

    auto loadA = [&](int c, uint4& x) {
        x = (c < 8) ? Abase[(size_t)c * 64] : Atail[0];
    };
    auto loadB = [&](int c, uint4 (&bb)[4]) {
        if (c < 8) {
            #pragma unroll
            for (int j = 0; j < 4; ++j)
                bb[j] = Bbase[((size_t)c * 16 + j) * 64];
        } else {
            #pragma unroll
            for (int j = 0; j < 4; ++j)
                bb[j] = *(const uint4*)(Btail + j * 512);
        }
    };
    auto doStep = [&](uint4 a, uint4 (&bb)[4]) {
        bf16x8 af = __builtin_bit_cast(bf16x8, a);
        #pragma unroll
        for (int j = 0; j < 4; ++j)
            acc[j] = __builtin_amdgcn_mfma_f32_16x16x32_bf16(
                af, __builtin_bit_cast(bf16x8, bb[j]), acc[j], 0, 0, 0);
    };

    uint4 a0, a1, a2, b0_[4], b1_[4], b2_[4];
    loadA(0, a0); loadB(0, b0_);
    loadA(1, a1); loadB(1, b1_);
    loadA(2, a2); loadB(2, b2_);
    #pragma unroll
    for (int base = 0; base < 9; base += 3) {
        uint4 na0, na1, na2, nb0[4], nb1[4], nb2[4];
        const bool pf = (base + 3) < 9;
        if (pf) { loadA(base + 3, na0); loadB(base + 3, nb0); }
        doStep(a0, b0_);
        if (pf) { loadA(base + 4, na1); loadB(base + 4, nb1); }
        doStep(a1, b1_);
        if (pf) { loadA(base + 5, na2); loadB(base + 5, nb2); }
        doStep(a2, b2_);
        if (pf) {
            a0 = na0; a1 = na1; a2 = na2;
            #pragma unroll
            for (int j = 0; j < 4; ++j) { b0_[j] = nb0[j]; b1_[j] = nb1[j]; b2_[j] = nb2[j]; }
        }
    }

    #pragma unroll
    for (int j = 0; j < 4; ++j) {
        float* o = out + (size_t)(b0 + w * 16 + kq * 4) * ZDIM + i0 + j * 16 + rl;
        #pragma unroll
        for (int r = 0; r < 4; ++r)
            o[(size_t)r * ZDIM] = -acc[j][r];
    }
}

// ---- K3 (MFMA, barrier-free): out[:, 2048:] ------------------------------------
// r9-proven structure, prefetch deepened to 3 steps (covers ~200cy L2 latency).
__global__ __launch_bounds__(256) void k_gemm_hi(
    const unsigned short* __restrict__ zf, const unsigned short* __restrict__ d1f,
    const unsigned short* __restrict__ Wf, const unsigned short* __restrict__ gW1b,
    float* __restrict__ out) {
    int t = threadIdx.x;
    int lane = t & 63;
    int w = t >> 6;
    int b0 = blockIdx.x * 64;
    int i0 = blockIdx.y * 64;

    int rl = lane & 15;
    int kq = lane >> 4;
    int rb = (b0 >> 4) + w;

    const uint4* Abase = (const uint4*)zf + (size_t)rb * 72 * 64 + lane;
    const uint4* Atail = (const uint4*)d1f + ((size_t)8 * 512 + rb) * 64 + lane;
    const uint4* Bbase = (const uint4*)Wf + (size_t)(i0 >> 4) * 64 + lane;

    f32x4 acc[4];
    #pragma unroll
    for (int j = 0; j < 4; ++j) acc[j] = (f32x4){0.f, 0.f, 0.f, 0.f};

    auto loadA = [&](int c, uint4& x) {
        x = (c < 64) ? Abase[(size_t)c * 64] : Atail[0];
    };
    auto loadB = [&](int c, uint4 (&bb)[4]) {
        if (c < 64) {
            #pragma unroll
            for (int j = 0; j < 4; ++j)
                bb[j] = Bbase[(size_t)c * 1024 + j * 64];
        } else {
            #pragma unroll
            for (int j = 0; j < 4; ++j)
                bb[j] = *(const uint4*)(gW1b + (size_t)(8 * 256 + i0 + j * 16 + rl) * 32 + kq * 8);
        }
    };
    auto doStep = [&](uint4 a, uint4 (&bb)[4]) {
        bf16x8 af = __builtin_bit_cast(bf16x8, a);
        #pragma unroll
        for (int j = 0; j < 4; ++j)
            acc[j] = __builtin_amdgcn_mfma_f32_16x16x32_bf16(
                af, __builtin_bit_cast(bf16x8, bb[j]), acc[j], 0, 0, 0);
    };

    uint4 a0, a1, a2, b0_[4], b1_[4], b2_[4];
    loadA(0, a0); loadB(0, b0_);
    loadA(1, a1); loadB(1, b1_);
    loadA(2, a2); loadB(2, b2_);
    for (int base = 0; base < 63; base += 3) {   // steps 0..62; epilogue 63,64
        uint4 na0, na1, na2, nb0[4], nb1[4], nb2[4];
        loadA(base + 3, na0); loadB(base + 3, nb0);
        doStep(a0, b0_);
        loadA(base + 4, na1); loadB(base + 4, nb1);
        doStep(a1, b1_);
        bool pf2 = (base + 5) < 65;
        if (pf2) { loadA(base + 5, na2); loadB(base + 5, nb2); }
        doStep(a2, b2_);
        a0 = na0; a1 = na1;
        #pragma unroll
        for (int j = 0; j < 4; ++j) { b0_[j] = nb0[j]; b1_[j] = nb1[j]; }
        if (pf2) {
            a2 = na2;
            #pragma unroll
            for (int j = 0; j < 4; ++j) b2_[j] = nb2[j];
        }
    }
    doStep(a0, b0_);   // step 63
    doStep(a1, b1_);   // step 64 (tail)

    #pragma unroll
    for (int j = 0; j < 4; ++j) {
        float* o = out + (size_t)(b0 + w * 16 + kq * 4) * ZDIM + 2048 + i0 + j * 16 + rl;
        #pragma unroll
        for (int r = 0; r < 4; ++r)
            o[(size_t)r * ZDIM] = -acc[j][r];
    }
}

extern "C" void kernel_launch(void* const* d_in, const int* in_sizes, int n_in,
                              void* d_out, int out_size, void* d_ws, size_t ws_size,
                              hipStream_t stream) {
    const float* z   = (const float*)d_in[0];
    const float* gW1 = (const float*)d_in[1];
    const float* gb1 = (const float*)d_in[2];
    const float* gW2 = (const float*)d_in[3];
    const float* gb2 = (const float*)d_in[4];
    const float* gW3 = (const float*)d_in[5];
    // d_in[6] = gb3: constant, no grad
    const float* W   = (const float*)d_in[7];
    float* out = (float*)d_out;

    unsigned short* d1f  = (unsigned short*)d_ws;            // 2359296 bf16 (fragment order)
    unsigned short* WTf  = d1f + 2359296;                    // 524288 bf16 (fragment order, lo)
    unsigned short* Wf   = WTf + 524288;                     // 524288 bf16 (fragment order, hi)
    unsigned short* gW1b = Wf + 524288;                      // 73728 bf16
    unsigned short* g1Tb = gW1b + 73728;                     // 73728 bf16
    unsigned short* zf   = g1Tb + 73728;                     // 18874368 bf16 (fragment order)

    k_pack<<<dim3(8, 8, 9), 256, 0, stream>>>(W, gW1, Wf, WTf, gW1b, g1Tb);
    k_mlp<<<dim3(128, 9), 256, 0, stream>>>(z, g1Tb, gb1, gW2, gb2, gW3, d1f, zf);
    k_gemm_lo<<<dim3(128, 32), 256, 0, stream>>>(zf, d1f, WTf, gW1b, out);
    k_gemm_hi<<<dim3(128, 4), 256, 0, stream>>>(zf, d1f, Wf, gW1b, out);
}